// Round 2
// baseline (1388.290 us; speedup 1.0000x reference)
//
#include <hip/hip_runtime.h>
#include <hip/hip_bf16.h>
#include <stdint.h>

#define B_    2
#define S_    4096
#define H_    16
#define NOPE  128
#define ROPE  64
#define QKD   192
#define VD    128
#define R_    512
#define KERW  32
#define STRW  16
#define NBLK  255
#define NSEL  64
#define TOPKN 16
#define SCALEF 0.07216878364870323f
#define BIGF   1000000000.0f

// ---------------------------------------------------------------------------
// G1: cmp_kv = window(kv_lora) @ W_cmp_kv   (M=510, N=512, K=16384)
// A-row (b,n) is contiguous: kv_lora + (b*S + n*STR)*R, length KER*R=16384.
// Tile 128x64, split-K=16 (chunk 1024), atomicAdd epilogue (out pre-zeroed).
// grid (4, 8, 16), block 256
// ---------------------------------------------------------------------------
__global__ __launch_bounds__(256) void g1_cmpkv(const float* __restrict__ A,
                                                const float* __restrict__ W,
                                                float* __restrict__ out) {
    __shared__ float As[16][132];
    __shared__ float Bs[16][68];
    const int t  = threadIdx.x;
    const int m0 = blockIdx.x * 128;
    const int n0 = blockIdx.y * 64;
    const int k0 = blockIdx.z * 1024;
    const int tr = t >> 4, tc = t & 15;   // rows 8*tr..+7, cols 4*tc..+3
    float acc[8][4];
#pragma unroll
    for (int i = 0; i < 8; ++i)
#pragma unroll
        for (int j = 0; j < 4; ++j) acc[i][j] = 0.f;

    for (int kt = 0; kt < 1024; kt += 16) {
        __syncthreads();
        // stage A: 128 rows x 16 k (transposed into [k][m])
#pragma unroll
        for (int i = 0; i < 2; ++i) {
            int f = t + i * 256;
            int r = f >> 2, kq = (f & 3) * 4;
            int m = m0 + r;
            float4 av = make_float4(0.f, 0.f, 0.f, 0.f);
            if (m < 510) {
                int b = (m >= NBLK) ? 1 : 0;
                int n = m - b * NBLK;
                av = *(const float4*)(A + (size_t)(b * S_ + n * STRW) * R_ + k0 + kt + kq);
            }
            As[kq + 0][r] = av.x; As[kq + 1][r] = av.y;
            As[kq + 2][r] = av.z; As[kq + 3][r] = av.w;
        }
        // stage B: 16 k x 64 n
        {
            int kb = t >> 4, nq = (t & 15) * 4;
            *(float4*)&Bs[kb][nq] =
                *(const float4*)(W + (size_t)(k0 + kt + kb) * R_ + n0 + nq);
        }
        __syncthreads();
#pragma unroll
        for (int kk = 0; kk < 16; ++kk) {
            float a0[8], b0[4];
            float4 x = *(const float4*)&As[kk][8 * tr];
            float4 y = *(const float4*)&As[kk][8 * tr + 4];
            a0[0] = x.x; a0[1] = x.y; a0[2] = x.z; a0[3] = x.w;
            a0[4] = y.x; a0[5] = y.y; a0[6] = y.z; a0[7] = y.w;
            float4 z = *(const float4*)&Bs[kk][4 * tc];
            b0[0] = z.x; b0[1] = z.y; b0[2] = z.z; b0[3] = z.w;
#pragma unroll
            for (int i = 0; i < 8; ++i)
#pragma unroll
                for (int j = 0; j < 4; ++j)
                    acc[i][j] = fmaf(a0[i], b0[j], acc[i][j]);
        }
    }
#pragma unroll
    for (int i = 0; i < 8; ++i) {
        int m = m0 + 8 * tr + i;
        if (m < 510) {
#pragma unroll
            for (int j = 0; j < 4; ++j)
                atomicAdd(&out[(size_t)m * R_ + n0 + 4 * tc + j], acc[i][j]);
        }
    }
}

// ---------------------------------------------------------------------------
// G1b: cmp_pe = window(k_pe) @ W_cmp_kpe   (M=510, N=64, K=2048)
// block 256 = 4 rows x 64 cols; grid 128
// ---------------------------------------------------------------------------
__global__ __launch_bounds__(256) void g1b_cmppe(const float* __restrict__ A,
                                                 const float* __restrict__ W,
                                                 float* __restrict__ out) {
    const int t = threadIdx.x;
    const int m = blockIdx.x * 4 + (t >> 6);
    const int col = t & 63;
    if (m >= 510) return;
    const int b = (m >= NBLK) ? 1 : 0;
    const int n = m - b * NBLK;
    const float* arow = A + (size_t)(b * S_ + n * STRW) * ROPE;
    float acc = 0.f;
    for (int k = 0; k < 2048; k += 4) {
        float4 a4 = *(const float4*)(arow + k);
        acc = fmaf(a4.x, W[(size_t)(k + 0) * 64 + col], acc);
        acc = fmaf(a4.y, W[(size_t)(k + 1) * 64 + col], acc);
        acc = fmaf(a4.z, W[(size_t)(k + 2) * 64 + col], acc);
        acc = fmaf(a4.w, W[(size_t)(k + 3) * 64 + col], acc);
    }
    out[(size_t)m * 64 + col] = acc;
}

// ---------------------------------------------------------------------------
// G2: kvb = cmp_kv @ W_kv_b  (M=510, N=4096, K=512), scatter into k_ws/v_ws.
// k_ws layout: ((b*16+h)*255 + n)*192 + d  (d<128 = nope, d>=128 filled by G2b)
// v_ws layout: ((b*16+h)*255 + n)*128 + j
// grid (8, 64), block 256, tile 64x64
// ---------------------------------------------------------------------------
__global__ __launch_bounds__(256) void g2_kvb(const float* __restrict__ A,
                                              const float* __restrict__ W,
                                              float* __restrict__ k_ws,
                                              float* __restrict__ v_ws) {
    __shared__ float As[16][68];
    __shared__ float Bs[16][68];
    const int t  = threadIdx.x;
    const int m0 = blockIdx.x * 64;
    const int n0 = blockIdx.y * 64;
    const int tr = t >> 4, tc = t & 15;
    float acc[4][4];
#pragma unroll
    for (int i = 0; i < 4; ++i)
#pragma unroll
        for (int j = 0; j < 4; ++j) acc[i][j] = 0.f;

    for (int kt = 0; kt < R_; kt += 16) {
        __syncthreads();
        {
            int r = t >> 2, kq = (t & 3) * 4;
            int m = m0 + r;
            float4 av = make_float4(0.f, 0.f, 0.f, 0.f);
            if (m < 510) av = *(const float4*)(A + (size_t)m * R_ + kt + kq);
            As[kq + 0][r] = av.x; As[kq + 1][r] = av.y;
            As[kq + 2][r] = av.z; As[kq + 3][r] = av.w;
        }
        {
            int kb = t >> 4, nq = (t & 15) * 4;
            *(float4*)&Bs[kb][nq] =
                *(const float4*)(W + (size_t)(kt + kb) * 4096 + n0 + nq);
        }
        __syncthreads();
#pragma unroll
        for (int kk = 0; kk < 16; ++kk) {
            float4 x = *(const float4*)&As[kk][4 * tr];
            float4 z = *(const float4*)&Bs[kk][4 * tc];
            float a0[4] = {x.x, x.y, x.z, x.w};
            float b0[4] = {z.x, z.y, z.z, z.w};
#pragma unroll
            for (int i = 0; i < 4; ++i)
#pragma unroll
                for (int j = 0; j < 4; ++j)
                    acc[i][j] = fmaf(a0[i], b0[j], acc[i][j]);
        }
    }
#pragma unroll
    for (int i = 0; i < 4; ++i) {
        int m = m0 + 4 * tr + i;
        if (m < 510) {
            int b = (m >= NBLK) ? 1 : 0;
            int n = m - b * NBLK;
#pragma unroll
            for (int j = 0; j < 4; ++j) {
                int c = n0 + 4 * tc + j;
                int h = c >> 8, jj = c & 255;
                size_t base = (size_t)((b * H_ + h) * NBLK + n);
                if (jj < NOPE) k_ws[base * QKD + jj] = acc[i][j];
                else           v_ws[base * VD + (jj - NOPE)] = acc[i][j];
            }
        }
    }
}

// G2b: broadcast cmp_pe into k_ws[..][128..191] for every head.
__global__ void g2b_pefill(const float* __restrict__ cmp_pe,
                           float* __restrict__ k_ws) {
    int gid = blockIdx.x * 256 + threadIdx.x;   // 522240 total, exact
    int rr = gid & 63;
    int rest = gid >> 6;
    int n = rest % NBLK;
    int bh = rest / NBLK;
    int b = bh >> 4;
    k_ws[((size_t)bh * NBLK + n) * QKD + NOPE + rr] =
        cmp_pe[((size_t)(b * NBLK + n)) * ROPE + rr];
}

// ---------------------------------------------------------------------------
// G3: attention per (b,h, 32-row tile): scores(fp32) -> masked softmax ->
//     p_agg atomicMax (head-max) -> O = P@V.
// grid (128, 32), block 256.  LDS ~106 KB (1 block/CU).
// Score phase: per 64-col chunk, thread = (row-pair tr = t&15) x (col-quad
// tcq = t>>4): 2 rows x 4 cols = 8 outputs/thread x 256 threads = 32x64.
// (Round-1 bug: previous mapping used 16-col groups -> OOB LDS reads.)
// ---------------------------------------------------------------------------
__global__ __launch_bounds__(256) void g3_attn(const float* __restrict__ q,
                                               const float* __restrict__ k_ws,
                                               const float* __restrict__ v_ws,
                                               float* __restrict__ o,
                                               unsigned int* __restrict__ p_agg) {
    __shared__ float qs[32][196];
    __shared__ float ks[64][196];   // reused for V chunks
    __shared__ float sc[32][258];
    const int t  = threadIdx.x;
    const int s0 = blockIdx.x * 32;
    const int bh = blockIdx.y;
    const int b = bh >> 4, h = bh & 15;

    // load Q tile (32 x 192)
    {
        const float* qbase = q + ((size_t)(b * S_ + s0) * H_ + h) * QKD;
        for (int f = t; f < 32 * 48; f += 256) {
            int r = f / 48, d4 = (f % 48) * 4;
            *(float4*)&qs[r][d4] =
                *(const float4*)(qbase + (size_t)r * (H_ * QKD) + d4);
        }
    }

    const int tr  = t & 15;   // rows 2*tr, 2*tr+1
    const int tcq = t >> 4;   // cols 4*tcq .. +3 (within 64-col chunk)

    for (int c = 0; c < 4; ++c) {
        __syncthreads();
        const float* kbase = k_ws + ((size_t)bh * NBLK + c * 64) * QKD;
        for (int f = t; f < 64 * 48; f += 256) {
            int n = f / 48, d4 = (f % 48) * 4;
            float4 v4 = make_float4(0.f, 0.f, 0.f, 0.f);
            if (c * 64 + n < NBLK) v4 = *(const float4*)(kbase + (size_t)n * QKD + d4);
            *(float4*)&ks[n][d4] = v4;
        }
        __syncthreads();
        float acc[2][4];
#pragma unroll
        for (int i = 0; i < 2; ++i)
#pragma unroll
            for (int cc = 0; cc < 4; ++cc) acc[i][cc] = 0.f;
        for (int d = 0; d < QKD; d += 4) {
            float4 q0 = *(const float4*)&qs[2 * tr][d];
            float4 q1 = *(const float4*)&qs[2 * tr + 1][d];
#pragma unroll
            for (int cc = 0; cc < 4; ++cc) {
                float4 k4 = *(const float4*)&ks[4 * tcq + cc][d];
                acc[0][cc] += q0.x * k4.x + q0.y * k4.y + q0.z * k4.z + q0.w * k4.w;
                acc[1][cc] += q1.x * k4.x + q1.y * k4.y + q1.z * k4.z + q1.w * k4.w;
            }
        }
#pragma unroll
        for (int i = 0; i < 2; ++i)
#pragma unroll
            for (int cc = 0; cc < 4; ++cc)
                sc[2 * tr + i][c * 64 + 4 * tcq + cc] = acc[i][cc] * SCALEF;
    }
    __syncthreads();

    // masked softmax, 8 threads per row; then head-max into p_agg
    {
        const int r = t >> 3, g = t & 7;
        const int s = s0 + r;
        const int nv = (s >= 31) ? (((s - 31) >> 4) + 1) : 0;  // # causal blocks
        float m = -INFINITY;
        for (int n = g; n < nv; n += 8) m = fmaxf(m, sc[r][n]);
#pragma unroll
        for (int off = 1; off < 8; off <<= 1) m = fmaxf(m, __shfl_xor(m, off, 8));
        float sum = 0.f;
        for (int n = g; n < nv; n += 8) {
            float p = __expf(sc[r][n] - m);
            sc[r][n] = p;
            sum += p;
        }
#pragma unroll
        for (int off = 1; off < 8; off <<= 1) sum += __shfl_xor(sum, off, 8);
        float inv = (nv > 0) ? (1.0f / sum) : 0.f;
        unsigned int* pa = p_agg + (size_t)(b * S_ + s) * NBLK;
        for (int n = g; n < 256; n += 8) {
            float p = (n < nv) ? sc[r][n] * inv : 0.f;
            sc[r][n] = p;
            if (n < nv) atomicMax(&pa[n], __float_as_uint(p));
        }
    }

    // O = probs @ V
    const int trr = t & 15;   // rows 2*trr, 2*trr+1
    const int tcv = t >> 4;   // cols 8*tcv .. +7
    float acco[2][8];
#pragma unroll
    for (int i = 0; i < 2; ++i)
#pragma unroll
        for (int j = 0; j < 8; ++j) acco[i][j] = 0.f;
    for (int c = 0; c < 4; ++c) {
        __syncthreads();
        const float* vbase = v_ws + ((size_t)bh * NBLK + c * 64) * VD;
        for (int f = t; f < 64 * 32; f += 256) {
            int n = f / 32, j4 = (f % 32) * 4;
            float4 v4 = make_float4(0.f, 0.f, 0.f, 0.f);
            if (c * 64 + n < NBLK) v4 = *(const float4*)(vbase + (size_t)n * VD + j4);
            *(float4*)&ks[n][j4] = v4;
        }
        __syncthreads();
        for (int n = 0; n < 64; ++n) {
            float p0 = sc[2 * trr][c * 64 + n];
            float p1 = sc[2 * trr + 1][c * 64 + n];
            float4 v0 = *(const float4*)&ks[n][8 * tcv];
            float4 v1 = *(const float4*)&ks[n][8 * tcv + 4];
            float vv[8] = {v0.x, v0.y, v0.z, v0.w, v1.x, v1.y, v1.z, v1.w};
#pragma unroll
            for (int j = 0; j < 8; ++j) {
                acco[0][j] = fmaf(p0, vv[j], acco[0][j]);
                acco[1][j] = fmaf(p1, vv[j], acco[1][j]);
            }
        }
    }
#pragma unroll
    for (int i = 0; i < 2; ++i) {
        int s = s0 + 2 * trr + i;
        float* dst = o + (size_t)(b * S_ + s) * (H_ * VD) + h * VD + 8 * tcv;
        *(float4*)dst = make_float4(acco[i][0], acco[i][1], acco[i][2], acco[i][3]);
        *(float4*)(dst + 4) = make_float4(acco[i][4], acco[i][5], acco[i][6], acco[i][7]);
    }
}

// ---------------------------------------------------------------------------
// G4: slc + forced/causal + top-16.  One wave per (b,s); lane j holds slc_j.
// Selection = repeated (wave-max, ballot, ffs) -> exactly top_k's
// value-desc / index-asc tie order.  grid 2048, block 256.
// ---------------------------------------------------------------------------
__global__ __launch_bounds__(256) void g4_topk(const float* __restrict__ p_agg,
                                               float* __restrict__ outI) {
    const int gid  = blockIdx.x * 256 + threadIdx.x;
    const int w    = gid >> 6;          // = b*S + s  (0..8191)
    const int lane = threadIdx.x & 63;  // = j
    const int s    = w & (S_ - 1);
    const float* pa = p_agg + (size_t)w * NBLK;
    const int j = lane;
    float slc = 0.f;
    int nlo = 4 * j - 1; if (nlo < 0) nlo = 0;
    int nhi = 4 * j + 3; if (nhi > NBLK - 1) nhi = NBLK - 1;
    for (int n = nlo; n <= nhi; ++n) slc += pa[n];
    const int jt = s >> 6;
    float val;
    if (j <= jt) val = ((j < 1) || (j >= jt - 1)) ? BIGF : slc;
    else         val = -BIGF;
    bool taken = false;
    float* dst = outI + (size_t)w * TOPKN;
    for (int kk = 0; kk < TOPKN; ++kk) {
        float v = taken ? -INFINITY : val;
        float m = v;
#pragma unroll
        for (int off = 32; off; off >>= 1) m = fmaxf(m, __shfl_xor(m, off, 64));
        unsigned long long msk = __ballot((!taken) && (val == m));
        int first = __ffsll(msk) - 1;
        if (lane == first) taken = true;
        if (lane == kk) dst[kk] = (m <= -BIGF * 0.5f) ? -1.0f : (float)first;
    }
}

// ---------------------------------------------------------------------------
extern "C" void kernel_launch(void* const* d_in, const int* in_sizes, int n_in,
                              void* d_out, int out_size, void* d_ws, size_t ws_size,
                              hipStream_t stream) {
    const float* q         = (const float*)d_in[0];
    const float* kv_lora   = (const float*)d_in[1];
    const float* k_pe      = (const float*)d_in[2];
    const float* W_cmp_kv  = (const float*)d_in[3];
    const float* W_cmp_kpe = (const float*)d_in[4];
    const float* W_kv_b    = (const float*)d_in[5];
    float* out = (float*)d_out;
    float* ws  = (float*)d_ws;

    float* cmp_kv = ws;                                  // 510*512   = 261120
    float* cmp_pe = ws + 261120;                         // 510*64    = 32640
    float* k_ws   = ws + 293760;                         // 32*255*192= 1566720
    float* v_ws   = ws + 1860480;                        // 32*255*128= 1044480
    unsigned int* p_agg = (unsigned int*)(ws + 2904960); // 2*4096*255= 2088960

    hipMemsetAsync(cmp_kv, 0, (size_t)261120 * 4, stream);
    hipMemsetAsync(p_agg, 0, (size_t)2088960 * 4, stream);

    g1_cmpkv <<<dim3(4, 8, 16), 256, 0, stream>>>(kv_lora, W_cmp_kv, cmp_kv);
    g1b_cmppe<<<dim3(128),      256, 0, stream>>>(k_pe, W_cmp_kpe, cmp_pe);
    g2_kvb   <<<dim3(8, 64),    256, 0, stream>>>(cmp_kv, W_kv_b, k_ws, v_ws);
    g2b_pefill<<<dim3(2040),    256, 0, stream>>>(cmp_pe, k_ws);
    g3_attn  <<<dim3(128, 32),  256, 0, stream>>>(q, k_ws, v_ws, out, p_agg);
    g4_topk  <<<dim3(2048),     256, 0, stream>>>((const float*)p_agg, out + 16777216);
}

// Round 3
// 774.049 us; speedup vs baseline: 1.7935x; 1.7935x over previous
//
#include <hip/hip_runtime.h>
#include <hip/hip_bf16.h>
#include <stdint.h>

#define B_    2
#define S_    4096
#define H_    16
#define NOPE  128
#define ROPE  64
#define QKD   192
#define VD    128
#define R_    512
#define KERW  32
#define STRW  16
#define NBLK  255
#define NSEL  64
#define TOPKN 16
#define SCALEF 0.07216878364870323f
#define BIGF   1000000000.0f

typedef __attribute__((ext_vector_type(8))) short bf8_t;   // 8 bf16 (4 VGPRs)
typedef __attribute__((ext_vector_type(4))) float f4_t;    // MFMA acc

#define MFB(a,b,c) __builtin_amdgcn_mfma_f32_16x16x32_bf16((a),(b),(c),0,0,0)

__device__ inline unsigned short f2bf(float x) {
    __hip_bfloat16 b = __float2bfloat16(x);
    return *reinterpret_cast<unsigned short*>(&b);
}
__device__ inline float bf2f(unsigned short u) {
    __hip_bfloat16 b = *reinterpret_cast<__hip_bfloat16*>(&u);
    return __bfloat162float(b);
}
// 3-way bf16 split: x ~= a + b + c with residual ~2^-26 rel
__device__ inline void split3f(float x, unsigned short& a, unsigned short& b,
                               unsigned short& c) {
    __hip_bfloat16 b0 = __float2bfloat16(x);
    float f0 = __bfloat162float(b0);
    float r1 = x - f0;
    __hip_bfloat16 b1 = __float2bfloat16(r1);
    float f1 = __bfloat162float(b1);
    float r2 = r1 - f1;
    __hip_bfloat16 b2 = __float2bfloat16(r2);
    a = *reinterpret_cast<unsigned short*>(&b0);
    b = *reinterpret_cast<unsigned short*>(&b1);
    c = *reinterpret_cast<unsigned short*>(&b2);
}

// ---------------------------------------------------------------------------
// G1: cmp_kv = window(kv_lora) @ W_cmp_kv   (M=510, N=512, K=16384)
// Tile 128x64, split-K=16, atomicAdd epilogue (out pre-zeroed).  (unchanged)
// ---------------------------------------------------------------------------
__global__ __launch_bounds__(256) void g1_cmpkv(const float* __restrict__ A,
                                                const float* __restrict__ W,
                                                float* __restrict__ out) {
    __shared__ float As[16][132];
    __shared__ float Bs[16][68];
    const int t  = threadIdx.x;
    const int m0 = blockIdx.x * 128;
    const int n0 = blockIdx.y * 64;
    const int k0 = blockIdx.z * 1024;
    const int tr = t >> 4, tc = t & 15;
    float acc[8][4];
#pragma unroll
    for (int i = 0; i < 8; ++i)
#pragma unroll
        for (int j = 0; j < 4; ++j) acc[i][j] = 0.f;

    for (int kt = 0; kt < 1024; kt += 16) {
        __syncthreads();
#pragma unroll
        for (int i = 0; i < 2; ++i) {
            int f = t + i * 256;
            int r = f >> 2, kq = (f & 3) * 4;
            int m = m0 + r;
            float4 av = make_float4(0.f, 0.f, 0.f, 0.f);
            if (m < 510) {
                int b = (m >= NBLK) ? 1 : 0;
                int n = m - b * NBLK;
                av = *(const float4*)(A + (size_t)(b * S_ + n * STRW) * R_ + k0 + kt + kq);
            }
            As[kq + 0][r] = av.x; As[kq + 1][r] = av.y;
            As[kq + 2][r] = av.z; As[kq + 3][r] = av.w;
        }
        {
            int kb = t >> 4, nq = (t & 15) * 4;
            *(float4*)&Bs[kb][nq] =
                *(const float4*)(W + (size_t)(k0 + kt + kb) * R_ + n0 + nq);
        }
        __syncthreads();
#pragma unroll
        for (int kk = 0; kk < 16; ++kk) {
            float a0[8], b0[4];
            float4 x = *(const float4*)&As[kk][8 * tr];
            float4 y = *(const float4*)&As[kk][8 * tr + 4];
            a0[0] = x.x; a0[1] = x.y; a0[2] = x.z; a0[3] = x.w;
            a0[4] = y.x; a0[5] = y.y; a0[6] = y.z; a0[7] = y.w;
            float4 z = *(const float4*)&Bs[kk][4 * tc];
            b0[0] = z.x; b0[1] = z.y; b0[2] = z.z; b0[3] = z.w;
#pragma unroll
            for (int i = 0; i < 8; ++i)
#pragma unroll
                for (int j = 0; j < 4; ++j)
                    acc[i][j] = fmaf(a0[i], b0[j], acc[i][j]);
        }
    }
#pragma unroll
    for (int i = 0; i < 8; ++i) {
        int m = m0 + 8 * tr + i;
        if (m < 510) {
#pragma unroll
            for (int j = 0; j < 4; ++j)
                atomicAdd(&out[(size_t)m * R_ + n0 + 4 * tc + j], acc[i][j]);
        }
    }
}

// ---------------------------------------------------------------------------
// G1b: cmp_pe = window(k_pe) @ W_cmp_kpe   (unchanged)
// ---------------------------------------------------------------------------
__global__ __launch_bounds__(256) void g1b_cmppe(const float* __restrict__ A,
                                                 const float* __restrict__ W,
                                                 float* __restrict__ out) {
    const int t = threadIdx.x;
    const int m = blockIdx.x * 4 + (t >> 6);
    const int col = t & 63;
    if (m >= 510) return;
    const int b = (m >= NBLK) ? 1 : 0;
    const int n = m - b * NBLK;
    const float* arow = A + (size_t)(b * S_ + n * STRW) * ROPE;
    float acc = 0.f;
    for (int k = 0; k < 2048; k += 4) {
        float4 a4 = *(const float4*)(arow + k);
        acc = fmaf(a4.x, W[(size_t)(k + 0) * 64 + col], acc);
        acc = fmaf(a4.y, W[(size_t)(k + 1) * 64 + col], acc);
        acc = fmaf(a4.z, W[(size_t)(k + 2) * 64 + col], acc);
        acc = fmaf(a4.w, W[(size_t)(k + 3) * 64 + col], acc);
    }
    out[(size_t)m * 64 + col] = acc;
}

// ---------------------------------------------------------------------------
// G2: kvb = cmp_kv @ W_kv_b; epilogue writes K as 3 bf16 planes
// kh/km/kl [bh][n][192] (d<128 here, rope part by g2b) and V transposed
// bf16 vT_g [bh][j][256] (n stride 1, col n=255 left unwritten: P[,255]=0).
// ---------------------------------------------------------------------------
__global__ __launch_bounds__(256) void g2_kvb(const float* __restrict__ A,
                                              const float* __restrict__ W,
                                              unsigned short* __restrict__ kh_g,
                                              unsigned short* __restrict__ km_g,
                                              unsigned short* __restrict__ kl_g,
                                              unsigned short* __restrict__ vT_g) {
    __shared__ float As[16][68];
    __shared__ float Bs[16][68];
    const int t  = threadIdx.x;
    const int m0 = blockIdx.x * 64;
    const int n0 = blockIdx.y * 64;
    const int tr = t >> 4, tc = t & 15;
    float acc[4][4];
#pragma unroll
    for (int i = 0; i < 4; ++i)
#pragma unroll
        for (int j = 0; j < 4; ++j) acc[i][j] = 0.f;

    for (int kt = 0; kt < R_; kt += 16) {
        __syncthreads();
        {
            int r = t >> 2, kq = (t & 3) * 4;
            int m = m0 + r;
            float4 av = make_float4(0.f, 0.f, 0.f, 0.f);
            if (m < 510) av = *(const float4*)(A + (size_t)m * R_ + kt + kq);
            As[kq + 0][r] = av.x; As[kq + 1][r] = av.y;
            As[kq + 2][r] = av.z; As[kq + 3][r] = av.w;
        }
        {
            int kb = t >> 4, nq = (t & 15) * 4;
            *(float4*)&Bs[kb][nq] =
                *(const float4*)(W + (size_t)(kt + kb) * 4096 + n0 + nq);
        }
        __syncthreads();
#pragma unroll
        for (int kk = 0; kk < 16; ++kk) {
            float4 x = *(const float4*)&As[kk][4 * tr];
            float4 z = *(const float4*)&Bs[kk][4 * tc];
            float a0[4] = {x.x, x.y, x.z, x.w};
            float b0[4] = {z.x, z.y, z.z, z.w};
#pragma unroll
            for (int i = 0; i < 4; ++i)
#pragma unroll
                for (int j = 0; j < 4; ++j)
                    acc[i][j] = fmaf(a0[i], b0[j], acc[i][j]);
        }
    }
#pragma unroll
    for (int i = 0; i < 4; ++i) {
        int m = m0 + 4 * tr + i;
        if (m < 510) {
            int b = (m >= NBLK) ? 1 : 0;
            int n = m - b * NBLK;
#pragma unroll
            for (int j = 0; j < 4; ++j) {
                int c = n0 + 4 * tc + j;
                int h = c >> 8, jj = c & 255;
                size_t bh = (size_t)(b * H_ + h);
                float x = acc[i][j];
                if (jj < NOPE) {
                    size_t idx = (bh * NBLK + n) * QKD + jj;
                    unsigned short u0, u1, u2;
                    split3f(x, u0, u1, u2);
                    kh_g[idx] = u0; km_g[idx] = u1; kl_g[idx] = u2;
                } else {
                    vT_g[(bh * VD + (jj - NOPE)) * 256 + n] = f2bf(x);
                }
            }
        }
    }
}

// G2b: rope part into K planes (d = 128..191), split3 per element.
__global__ void g2b_pefill(const float* __restrict__ cmp_pe,
                           unsigned short* __restrict__ kh_g,
                           unsigned short* __restrict__ km_g,
                           unsigned short* __restrict__ kl_g) {
    int gid = blockIdx.x * 256 + threadIdx.x;   // 522240 total, exact
    int rr = gid & 63;
    int rest = gid >> 6;
    int n = rest % NBLK;
    int bh = rest / NBLK;
    int b = bh >> 4;
    float x = cmp_pe[((size_t)(b * NBLK + n)) * ROPE + rr];
    size_t idx = ((size_t)bh * NBLK + n) * QKD + NOPE + rr;
    unsigned short u0, u1, u2;
    split3f(x, u0, u1, u2);
    kh_g[idx] = u0; km_g[idx] = u1; kl_g[idx] = u2;
}

// ---------------------------------------------------------------------------
// G3: MFMA attention.  Per (b,h,32-row tile), 512 threads (8 waves).
// Scores: bf16 triple-split, 6-term MFMA emulation (~1e-7 rel = fp32-class,
// protects topk ordering).  Softmax exact fp32.  PV: plain bf16 MFMA.
// LDS phases:  A: q planes(38.4K)+k planes(76.8K)+sc_f32(33K)
//              B: softmax reads sc_f32, writes scb bf16 (overlaid on q)
//              C: vT(67.6K, overlaid on q/k) + PV.   Total 148224 B.
// Fragment layouts (learn_hip m89/m120 verified):
//   A[m=lane&15][k=quad*8+j], B[n=lane&15][k=quad*8+j],
//   C/D: col=lane&15, row=quad*4+reg.
// ---------------------------------------------------------------------------
__global__ __launch_bounds__(512) void g3_attn(const float* __restrict__ q,
                                               const unsigned short* __restrict__ kh_g,
                                               const unsigned short* __restrict__ km_g,
                                               const unsigned short* __restrict__ kl_g,
                                               const unsigned short* __restrict__ vT_g,
                                               float* __restrict__ o,
                                               unsigned int* __restrict__ p_agg) {
    __shared__ __attribute__((aligned(16))) char smem[148224];
    float* sc           = (float*)smem;                                  // [32][258]
    unsigned short* qpl = (unsigned short*)(smem + 33024);               // 3x[32][200]
    unsigned short* kpl = (unsigned short*)(smem + 33024 + 38400);       // 3x[64][200]
    unsigned short* scb = (unsigned short*)(smem + 33024);               // [32][264]
    unsigned short* vT  = (unsigned short*)(smem + 33024 + 16896);       // [128][264]

    const int t  = threadIdx.x;
    const int s0 = blockIdx.x * 32;
    const int bh = blockIdx.y;
    const int b = bh >> 4, h = bh & 15;

    // ---- stage Q (32x192 fp32 -> 3 bf16 planes, stride 200) ----
    for (int f = t; f < 1536; f += 512) {
        int r = f / 48, c4 = (f % 48) * 4;
        float4 v = *(const float4*)(q + ((size_t)(b * S_ + s0 + r) * H_ + h) * QKD + c4);
        ushort4 uh, um, ul;
        split3f(v.x, uh.x, um.x, ul.x);
        split3f(v.y, uh.y, um.y, ul.y);
        split3f(v.z, uh.z, um.z, ul.z);
        split3f(v.w, uh.w, um.w, ul.w);
        int base = r * 200 + c4;
        *(ushort4*)(qpl + base)         = uh;
        *(ushort4*)(qpl + 6400 + base)  = um;
        *(ushort4*)(qpl + 12800 + base) = ul;
    }

    const int wave = t >> 6, lane = t & 63;
    const int ln = lane & 15, quad = lane >> 4;
    const int mt = wave >> 2, nt = wave & 3;   // score: m-tile, n-tile

    // ---- score phase: 4 chunks of 64 K-rows ----
    for (int c = 0; c < 4; ++c) {
        __syncthreads();
        for (int f = t; f < 1536; f += 512) {
            int n = f / 24, seg = (f % 24) * 8;
            int gn = c * 64 + n;
            uint4 a0 = make_uint4(0, 0, 0, 0), a1 = a0, a2 = a0;
            if (gn < NBLK) {
                size_t gidx = ((size_t)(bh * NBLK + gn)) * QKD + seg;
                a0 = *(const uint4*)(kh_g + gidx);
                a1 = *(const uint4*)(km_g + gidx);
                a2 = *(const uint4*)(kl_g + gidx);
            }
            int lbase = n * 200 + seg;
            *(uint4*)(kpl + lbase)         = a0;
            *(uint4*)(kpl + 12800 + lbase) = a1;
            *(uint4*)(kpl + 25600 + lbase) = a2;
        }
        __syncthreads();
        f4_t acc = {0.f, 0.f, 0.f, 0.f};
        const unsigned short* abase = qpl + (16 * mt + ln) * 200 + quad * 8;
        const unsigned short* bbase = kpl + (16 * nt + ln) * 200 + quad * 8;
#pragma unroll
        for (int kk = 0; kk < 6; ++kk) {
            bf8_t ah = *(const bf8_t*)(abase + kk * 32);
            bf8_t am = *(const bf8_t*)(abase + 6400 + kk * 32);
            bf8_t al = *(const bf8_t*)(abase + 12800 + kk * 32);
            bf8_t bh_ = *(const bf8_t*)(bbase + kk * 32);
            bf8_t bm = *(const bf8_t*)(bbase + 12800 + kk * 32);
            bf8_t bl = *(const bf8_t*)(bbase + 25600 + kk * 32);
            acc = MFB(ah, bh_, acc);
            acc = MFB(ah, bm, acc);
            acc = MFB(am, bh_, acc);
            acc = MFB(ah, bl, acc);
            acc = MFB(am, bm, acc);
            acc = MFB(al, bh_, acc);
        }
        int row0 = 16 * mt + 4 * quad;
        int col = c * 64 + 16 * nt + ln;
#pragma unroll
        for (int r = 0; r < 4; ++r)
            sc[(row0 + r) * 258 + col] = acc[r] * SCALEF;
    }
    __syncthreads();

    // ---- softmax (fp32, 16 threads/row) -> p_agg (fp32) + scb (bf16) ----
    {
        int r = t >> 4, g = t & 15;
        int s = s0 + r;
        int nv = (s >= 31) ? (((s - 31) >> 4) + 1) : 0;
        float m = -INFINITY;
        for (int n = g; n < nv; n += 16) m = fmaxf(m, sc[r * 258 + n]);
#pragma unroll
        for (int off = 1; off < 16; off <<= 1) m = fmaxf(m, __shfl_xor(m, off, 16));
        float sum = 0.f;
        for (int n = g; n < nv; n += 16) {
            float p = __expf(sc[r * 258 + n] - m);
            sc[r * 258 + n] = p;
            sum += p;
        }
#pragma unroll
        for (int off = 1; off < 16; off <<= 1) sum += __shfl_xor(sum, off, 16);
        float inv = (nv > 0) ? (1.0f / sum) : 0.f;
        unsigned int* pa = p_agg + (size_t)(b * S_ + s) * NBLK;
        for (int n = g; n < 256; n += 16) {
            float p = (n < nv) ? sc[r * 258 + n] * inv : 0.f;
            scb[r * 264 + n] = f2bf(p);
            if (n < nv) atomicMax(&pa[n], __float_as_uint(p));
        }
    }

    // ---- stage vT (128 x 256 bf16; n=255 col is garbage * p=0 = 0) ----
    for (int f = t; f < 4096; f += 512) {
        int j = f >> 5, seg = (f & 31) * 8;
        *(uint4*)(vT + j * 264 + seg) =
            *(const uint4*)(vT_g + ((size_t)(bh * VD + j)) * 256 + seg);
    }
    __syncthreads();

    // ---- PV: O(32x128) = P(32x256) @ V(256x128), bf16 MFMA ----
    {
        const int jt0 = 2 * nt;   // wave handles j-tiles jt0, jt0+1; m-tile mt
        f4_t oa0 = {0.f, 0.f, 0.f, 0.f}, oa1 = oa0;
        const unsigned short* pabase = scb + (16 * mt + ln) * 264 + quad * 8;
        const unsigned short* vb0 = vT + (16 * jt0 + ln) * 264 + quad * 8;
        const unsigned short* vb1 = vT + (16 * (jt0 + 1) + ln) * 264 + quad * 8;
#pragma unroll
        for (int kk = 0; kk < 8; ++kk) {
            bf8_t a = *(const bf8_t*)(pabase + kk * 32);
            bf8_t b0 = *(const bf8_t*)(vb0 + kk * 32);
            bf8_t b1 = *(const bf8_t*)(vb1 + kk * 32);
            oa0 = MFB(a, b0, oa0);
            oa1 = MFB(a, b1, oa1);
        }
        int row0 = s0 + 16 * mt + 4 * quad;
#pragma unroll
        for (int r = 0; r < 4; ++r) {
            size_t rbase = (size_t)(b * S_ + row0 + r) * 2048 + h * VD;
            o[rbase + 16 * jt0 + ln] = oa0[r];
            o[rbase + 16 * (jt0 + 1) + ln] = oa1[r];
        }
    }
}

// ---------------------------------------------------------------------------
// G4: slc + forced/causal + top-16.  (unchanged)
// ---------------------------------------------------------------------------
__global__ __launch_bounds__(256) void g4_topk(const float* __restrict__ p_agg,
                                               float* __restrict__ outI) {
    const int gid  = blockIdx.x * 256 + threadIdx.x;
    const int w    = gid >> 6;          // = b*S + s
    const int lane = threadIdx.x & 63;  // = j
    const int s    = w & (S_ - 1);
    const float* pa = p_agg + (size_t)w * NBLK;
    const int j = lane;
    float slc = 0.f;
    int nlo = 4 * j - 1; if (nlo < 0) nlo = 0;
    int nhi = 4 * j + 3; if (nhi > NBLK - 1) nhi = NBLK - 1;
    for (int n = nlo; n <= nhi; ++n) slc += pa[n];
    const int jt = s >> 6;
    float val;
    if (j <= jt) val = ((j < 1) || (j >= jt - 1)) ? BIGF : slc;
    else         val = -BIGF;
    bool taken = false;
    float* dst = outI + (size_t)w * TOPKN;
    for (int kk = 0; kk < TOPKN; ++kk) {
        float v = taken ? -INFINITY : val;
        float m = v;
#pragma unroll
        for (int off = 32; off; off >>= 1) m = fmaxf(m, __shfl_xor(m, off, 64));
        unsigned long long msk = __ballot((!taken) && (val == m));
        int first = __ffsll(msk) - 1;
        if (lane == first) taken = true;
        if (lane == kk) dst[kk] = (m <= -BIGF * 0.5f) ? -1.0f : (float)first;
    }
}

// ---------------------------------------------------------------------------
extern "C" void kernel_launch(void* const* d_in, const int* in_sizes, int n_in,
                              void* d_out, int out_size, void* d_ws, size_t ws_size,
                              hipStream_t stream) {
    const float* q         = (const float*)d_in[0];
    const float* kv_lora   = (const float*)d_in[1];
    const float* k_pe      = (const float*)d_in[2];
    const float* W_cmp_kv  = (const float*)d_in[3];
    const float* W_cmp_kpe = (const float*)d_in[4];
    const float* W_kv_b    = (const float*)d_in[5];
    float* out = (float*)d_out;
    char* W = (char*)d_ws;

    // byte offsets (all 16-aligned)
    float* cmp_kv        = (float*)W;                         // 1,044,480 B
    float* cmp_pe        = (float*)(W + 1044480);             //   130,560 B
    unsigned int* p_agg  = (unsigned int*)(W + 1175040);      // 8,355,840 B
    unsigned short* kh_g = (unsigned short*)(W + 9530880);    // 3,133,440 B
    unsigned short* km_g = (unsigned short*)(W + 12664320);   // 3,133,440 B
    unsigned short* kl_g = (unsigned short*)(W + 15797760);   // 3,133,440 B
    unsigned short* vT_g = (unsigned short*)(W + 18931200);   // 2,097,152 B
                                                              // end 21,028,352 B

    hipMemsetAsync(cmp_kv, 0, (size_t)1044480, stream);
    hipMemsetAsync(p_agg, 0, (size_t)8355840, stream);

    g1_cmpkv  <<<dim3(4, 8, 16), 256, 0, stream>>>(kv_lora, W_cmp_kv, cmp_kv);
    g1b_cmppe <<<dim3(128),      256, 0, stream>>>(k_pe, W_cmp_kpe, cmp_pe);
    g2_kvb    <<<dim3(8, 64),    256, 0, stream>>>(cmp_kv, W_kv_b, kh_g, km_g, kl_g, vT_g);
    g2b_pefill<<<dim3(2040),     256, 0, stream>>>(cmp_pe, kh_g, km_g, kl_g);
    g3_attn   <<<dim3(128, 32),  512, 0, stream>>>(q, kh_g, km_g, kl_g, vT_g, out, p_agg);
    g4_topk   <<<dim3(2048),     256, 0, stream>>>((const float*)p_agg, out + 16777216);
}